// Round 3
// baseline (604.177 us; speedup 1.0000x reference)
//
#include <hip/hip_runtime.h>

// Quantum-LSTM forward. 512 blocks x 4 waves, 1 sample/block, verified
// constants from rounds 1-2. Round-3 changes:
//  1. amdgpu_waves_per_eu(2,2) + inline-asm "+v" pins: the merged-gate
//     coefficients (96 floats) and Wc row stay RESIDENT in VGPRs (round-2's
//     VGPR_Count=76 proved the compiler was rematerializing them per stage).
//  2. State as float2 ext_vector -> v_pk_fma_f32 packed math in the gate
//     chain and embedding (falls back to scalar harmlessly).
//  3. Embedding via factor = E + sgn*F: lanes 0-5 publish one float4 per
//     wire to a wave-private LDS slot (no barrier needed), all lanes read
//     broadcast; replaces the readlane+cndmask chains.

namespace {

constexpr int BATCH  = 512;
constexpr int TSTEPS = 256;

typedef float v2f __attribute__((ext_vector_type(2)));

__device__ __forceinline__ v2f splat2(float s) { v2f r; r.x = s; r.y = s; return r; }
__device__ __forceinline__ v2f cswapneg(v2f v) { v2f r; r.x = -v.y; r.y = v.x; return r; }

__device__ __forceinline__ float sigf(float v) { return 1.0f / (1.0f + __expf(-v)); }
__device__ __forceinline__ float tanh_fast(float v) { return 1.0f - 2.0f / (1.0f + __expf(v + v)); }

template<int M>
__device__ __forceinline__ float shx(float v, int lane4) {
  if constexpr (M < 32) {
    return __int_as_float(__builtin_amdgcn_ds_swizzle(__float_as_int(v), 0x1F | (M << 10)));
  } else {
    return __int_as_float(__builtin_amdgcn_ds_bpermute(lane4 ^ (M << 2), __float_as_int(v)));
  }
}

// u = K0 v + K1 v^M1 + K2 v^M2 + K3 v^(M1^M2)  (complex, packed)
template<int M1, int M2, int M12>
__device__ __forceinline__ void stagep(v2f& s, float4 kA, float4 kB, int lane4) {
  v2f v1, v2, v3;
  v1.x = shx<M1>(s.x, lane4);  v1.y = shx<M1>(s.y, lane4);
  v2.x = shx<M2>(s.x, lane4);  v2.y = shx<M2>(s.y, lane4);
  v3.x = shx<M12>(s.x, lane4); v3.y = shx<M12>(s.y, lane4);
  v2f u = splat2(kA.x) * s;
  u = __builtin_elementwise_fma(splat2(kA.y), cswapneg(s),  u);
  u = __builtin_elementwise_fma(splat2(kA.z), v1,           u);
  u = __builtin_elementwise_fma(splat2(kA.w), cswapneg(v1), u);
  u = __builtin_elementwise_fma(splat2(kB.x), v2,           u);
  u = __builtin_elementwise_fma(splat2(kB.y), cswapneg(v2), u);
  u = __builtin_elementwise_fma(splat2(kB.z), v3,           u);
  u = __builtin_elementwise_fma(splat2(kB.w), cswapneg(v3), u);
  s = u;
}

__device__ __forceinline__ void gate_chain(v2f& s,
    const float4 (&kA)[6], const float4 (&kB)[6], int lane4) {
  stagep<0x0F,0x1E,0x11>(s, kA[0], kB[0], lane4);
  stagep<0x3C,0x3B,0x07>(s, kA[1], kB[1], lane4);
  stagep<0x3F,0x3D,0x02>(s, kA[2], kB[2], lane4);
  stagep<0x16,0x26,0x30>(s, kA[3], kB[3], lane4);
  stagep<0x05,0x28,0x2D>(s, kA[4], kB[4], lane4);
  stagep<0x14,0x0A,0x1E>(s, kA[5], kB[5], lane4);
}

// merged FWHT + final gather
__device__ __forceinline__ float expvals(v2f s, const float (&fs)[9],
                                         int lane4, int gaddr) {
  float p  = fmaf(s.x, s.x, s.y * s.y);
  float pa = shx<1>(p, lane4), pb = shx<2>(p, lane4), pc = shx<3>(p, lane4);
  p = fmaf(fs[0], p, fmaf(fs[1], pa, fmaf(fs[2], pb, pc)));
  pa = shx<4>(p, lane4); pb = shx<8>(p, lane4); pc = shx<12>(p, lane4);
  p = fmaf(fs[3], p, fmaf(fs[4], pa, fmaf(fs[5], pb, pc)));
  pa = shx<16>(p, lane4); pb = shx<32>(p, lane4); pc = shx<48>(p, lane4);
  p = fmaf(fs[6], p, fmaf(fs[7], pa, fmaf(fs[8], pb, pc)));
  return __int_as_float(__builtin_amdgcn_ds_bpermute(gaddr, __float_as_int(p)));
}

// per-wire embedding factor as (Er, Ei, Fr, Fi); factor(bit) = E + sgn*F,
// sgn=+1 for bit=0 (-> A - iB), sgn=-1 for bit=1 (-> C + iD)
__device__ __forceinline__ float4 trigEF(float Xv) {
  float tq   = Xv * Xv;
  float cth1 = rsqrtf(1.f + tq);
  float sth1 = Xv * cth1;
  float u1   = 1.f + cth1, r1 = rsqrtf(u1 + u1);
  float c1   = u1 * r1,    s1 = sth1 * r1;     // cos/sin(atan(x)/2)
  float tq2  = tq * tq;
  float cth2 = rsqrtf(1.f + tq2);
  float sth2 = tq * cth2;
  float u2   = 1.f + cth2, r2 = rsqrtf(u2 + u2);
  float c2   = u2 * r2,    s2 = sth2 * r2;     // cos/sin(atan(x^2)/2)
  float up = 0.5f * (c1 + s1), um = 0.5f * (c1 - s1);
  return make_float4(c2 * up, -s2 * um, c2 * um, -s2 * up);
}

// product-state embedding from the 6 published EF float4s (wave-private LDS)
__device__ __forceinline__ v2f embedEF(const float4* __restrict__ efw,
                                       const float (&sgn)[6]) {
  float4 e0 = efw[0];
  v2f s;
  s.x = fmaf(sgn[0], e0.z, e0.x);
  s.y = fmaf(sgn[0], e0.w, e0.y);
#pragma unroll
  for (int k = 1; k < 6; ++k) {
    float4 e = efw[k];
    float fr = fmaf(sgn[k], e.z, e.x);
    float fi = fmaf(sgn[k], e.w, e.y);
    v2f t = splat2(fr) * s;
    s = __builtin_elementwise_fma(splat2(fi), cswapneg(s), t);
  }
  return s;
}

// per-lane merged-pair coefficients for one circuit (reads fG in LDS, once)
__device__ __forceinline__ void make_K(const float4* fgc, int lane,
                                       float4 (&kA)[6], float4 (&kB)[6]) {
  constexpr unsigned BM[2][6] = {
    {0x18,0x30,0x39,0x0C,0x26,0x33},
    {0x2A,0x15,0x01,0x35,0x3A,0x3D}};
#pragma unroll
  for (int s = 0; s < 6; ++s) {
    int l = s / 3, i0 = (s % 3) * 2;
    float4 ga1 = fgc[(l*6+i0)*2],     gb1 = fgc[(l*6+i0)*2+1];
    float4 ga2 = fgc[(l*6+i0+1)*2],   gb2 = fgc[(l*6+i0+1)*2+1];
    bool p1 = __popc(lane & (int)BM[l][i0])   & 1;
    bool p2 = __popc(lane & (int)BM[l][i0+1]) & 1;
    float arr = p1 ? gb1.z : ga1.x, ari = p1 ? gb1.w : ga1.y;
    float brr = p1 ? gb1.x : ga1.z, bri = p1 ? gb1.y : ga1.w;
    float crr = p2 ? gb2.z : ga2.x, cri = p2 ? gb2.w : ga2.y;
    float drr = p2 ? gb2.x : ga2.z, dri = p2 ? gb2.y : ga2.w;
    kA[s] = make_float4(crr*arr - cri*ari, crr*ari + cri*arr,
                        crr*brr - cri*bri, crr*bri + cri*brr);
    kB[s] = make_float4(drr*arr - dri*ari, drr*ari + dri*arr,
                        drr*brr - dri*bri, drr*bri + dri*brr);
  }
}

#define PACK_IDX ((0x2AULL)|(0x15ULL<<6)|(0x01ULL<<12)|(0x35ULL<<18)|(0x3AULL<<24)|(0x3DULL<<30))
#define PIN4(v) asm volatile("" : "+v"((v).x), "+v"((v).y), "+v"((v).z), "+v"((v).w))

} // namespace

__global__ __attribute__((amdgpu_flat_work_group_size(256, 256)))
           __attribute__((amdgpu_waves_per_eu(2, 2)))
void qlstm_kernel(const float* __restrict__ x, const float* __restrict__ phi,
                  const float* __restrict__ Wc, const float* __restrict__ bc,
                  float* __restrict__ out)
{
  __shared__ float4 fG[144];       // 6 circuits x 12 gates x {G00G01, G10G11}
  __shared__ float4 ef_s[4][8];    // wave-private EF broadcast slots (6 used)
  __shared__ float4 gates4[6];     // per-wire (f,i,C,o), sigmoided
  __shared__ float  h_s[6];

  const int tid   = threadIdx.x;
  const int wave  = tid >> 6;
  const int lane  = tid & 63;
  const int lane4 = lane << 2;
  const int b     = blockIdx.x;

  // ---- one-time: fused gate matrices G = RZ*RY*RX per (circuit,layer,wire) ----
  if (tid < 72) {
    int g = tid / 12, rem = tid % 12, l = rem / 6, i = rem % 6;
    const float* w = phi + g*36 + l*18 + i*3;
    float sa, ca, sb, cb, sc, cc;
    sincosf(0.5f * w[0], &sa, &ca);
    sincosf(0.5f * w[1], &sb, &cb);
    sincosf(0.5f * w[2], &sc, &cc);
    float m00r =  cb*ca, m00i =  sb*sa;
    float m01r = -sb*ca, m01i = -cb*sa;
    float m10r =  sb*ca, m10i = -cb*sa;
    float m11r =  cb*ca, m11i = -sb*sa;
    float4 A, Bv;
    A.x  = m00r*cc + m00i*sc;  A.y  = m00i*cc - m00r*sc;
    A.z  = m01r*cc + m01i*sc;  A.w  = m01i*cc - m01r*sc;
    Bv.x = m10r*cc - m10i*sc;  Bv.y = m10i*cc + m10r*sc;
    Bv.z = m11r*cc - m11i*sc;  Bv.w = m11i*cc + m11r*sc;
    fG[2*tid] = A; fG[2*tid+1] = Bv;
  }
  if (tid < 6) h_s[tid] = 0.f;
  __syncthreads();

  // ---- per-wave/lane loop-invariants ----
  const int j = (lane < 6) ? lane : 0;           // owned wire
  float Wr[14];
#pragma unroll
  for (int k = 0; k < 14; ++k) Wr[k] = Wc[j*14 + k];
  const float bcj = bc[j];

  float sgn[6];
#pragma unroll
  for (int k = 0; k < 6; ++k) sgn[k] = ((lane >> k) & 1) ? -1.f : 1.f;
  float fs[9] = { sgn[0]*sgn[1], sgn[1], sgn[0],
                  sgn[2]*sgn[3], sgn[3], sgn[2],
                  sgn[4]*sgn[5], sgn[5], sgn[4] };

  int sh    = (lane < 6) ? (6 * lane) : 0;
  int gaddr = (int)((PACK_IDX >> sh) & 63ULL) << 2;

  float4 kA1[6], kB1[6], kA2[6], kB2[6];
  make_K(&fG[wave * 24], lane, kA1, kB1);                 // phase-1 circuit
  make_K(&fG[(4 + (wave & 1)) * 24], lane, kA2, kB2);     // phase-2 circuit
#pragma unroll
  for (int s = 0; s < 6; ++s) { PIN4(kA1[s]); PIN4(kB1[s]); PIN4(kA2[s]); PIN4(kB2[s]); }
#pragma unroll
  for (int k = 0; k < 14; ++k) asm volatile("" : "+v"(Wr[k]));

  float c_sc  = 0.f;   // lane i (<6) of waves 0,1 owns c_i
  float hlast = 0.f;

  const float* xbase = x + (size_t)b * TSTEPS * 8;
  float4 xa = *(const float4*)(xbase);
  float4 xb = *(const float4*)(xbase + 4);

  float4* efw = &ef_s[wave][0];

  for (int t = 0; t < TSTEPS; ++t) {
    // ---- phase 1: X_j in lane j, publish EF, circuit (f,i,C,o per wave) ----
    float hv0 = h_s[0], hv1 = h_s[1], hv2 = h_s[2];
    float hv3 = h_s[3], hv4 = h_s[4], hv5 = h_s[5];
    float acc = bcj;
    acc = fmaf(xa.x, Wr[0],  acc); acc = fmaf(xa.y, Wr[1],  acc);
    acc = fmaf(xa.z, Wr[2],  acc); acc = fmaf(xa.w, Wr[3],  acc);
    acc = fmaf(xb.x, Wr[4],  acc); acc = fmaf(xb.y, Wr[5],  acc);
    acc = fmaf(xb.z, Wr[6],  acc); acc = fmaf(xb.w, Wr[7],  acc);
    acc = fmaf(hv0,  Wr[8],  acc); acc = fmaf(hv1,  Wr[9],  acc);
    acc = fmaf(hv2,  Wr[10], acc); acc = fmaf(hv3,  Wr[11], acc);
    acc = fmaf(hv4,  Wr[12], acc); acc = fmaf(hv5,  Wr[13], acc);
    float Xj = 1.f - 2.f / (1.f + __expf(acc));

    // prefetch next x (overlaps the circuit)
    int tn = (t + 1 < TSTEPS) ? (t + 1) : t;
    float4 xa_n = *(const float4*)(xbase + (size_t)tn * 8);
    float4 xb_n = *(const float4*)(xbase + (size_t)tn * 8 + 4);

    float4 ef = trigEF(Xj);
    if (lane < 6) efw[lane] = ef;
    v2f s = embedEF(efw, sgn);
    gate_chain(s, kA1, kB1, lane4);
    float Wv  = expvals(s, fs, lane4, gaddr);
    float sgv = sigf(Wv);
    if (lane < 6) ((float*)&gates4[lane])[wave] = sgv;
    __syncthreads();

    // ---- phase 2: cell update + circuits h (wave0), y (wave1) ----
    if (wave < 2) {
      float4 g4 = gates4[j];                       // (f,i,C,o) for wire j
      float cn  = fmaf(g4.x, c_sc, g4.y * g4.z);
      c_sc = cn;
      float resc = g4.w * tanh_fast(cn);
      float4 ef2 = trigEF(resc);
      if (lane < 6) efw[lane] = ef2;
      v2f s2 = embedEF(efw, sgn);
      gate_chain(s2, kA2, kB2, lane4);
      float Wv2 = expvals(s2, fs, lane4, gaddr);
      if (wave == 0) {
        if (lane < 6) h_s[lane] = Wv2;
        hlast = Wv2;
      } else if (lane < 6) {
        out[((size_t)b * TSTEPS + t) * 6 + lane] = Wv2;
      }
    }
    xa = xa_n; xb = xb_n;
    __syncthreads();
  }

  // ---- final c, h ----
  if (wave == 0 && lane < 6) {
    size_t cbase = (size_t)BATCH * TSTEPS * 6;
    out[cbase + (size_t)b * 6 + lane] = c_sc;
    out[cbase + (size_t)BATCH * 6 + (size_t)b * 6 + lane] = hlast;
  }
}

extern "C" void kernel_launch(void* const* d_in, const int* in_sizes, int n_in,
                              void* d_out, int out_size, void* d_ws, size_t ws_size,
                              hipStream_t stream) {
  const float* x   = (const float*)d_in[0];
  const float* phi = (const float*)d_in[1];
  const float* Wc  = (const float*)d_in[2];
  const float* bc  = (const float*)d_in[3];
  float* out = (float*)d_out;
  (void)in_sizes; (void)n_in; (void)out_size; (void)d_ws; (void)ws_size;
  hipLaunchKernelGGL(qlstm_kernel, dim3(BATCH), dim3(256), 0, stream,
                     x, phi, Wc, bc, out);
}